// Round 5
// baseline (104.950 us; speedup 1.0000x reference)
//
#include <hip/hip_runtime.h>
#include <math.h>

#define EPS_F 1e-6f
#define S_DIM 768
#define W_DIM 32
#define H_DIM 12
#define NK 33   // intervals = W_DIM + 1

// ws float layout:
//   [0 .. 32)                      sorted hinge values (ascending)
//   [32 + h*2*NK + 2k]  = A_k(h)   (slope)
//   [32 + h*2*NK + 2k+1]= B_k(h)   (intercept, includes b_out[h])

// ---------------- setup: build sorted hinges + per-(h,k) PWL tables ----------
__global__ __launch_bounds__(512) void cope_setup_kernel(
    const float* __restrict__ W_in, const float* __restrict__ b_in,
    const float* __restrict__ W_out, const float* __restrict__ b_out,
    float* __restrict__ ws)
{
    __shared__ float th[W_DIM];
    __shared__ int   rk[W_DIM];
    const int t = threadIdx.x;

    if (t < W_DIM) {
        float w1 = W_in[t], b = b_in[t];
        th[t] = (w1 != 0.0f) ? (-b / w1) : __builtin_inff();
    }
    __syncthreads();

    if (t < W_DIM) {
        float mine = th[t];
        int r = 0;
        for (int v = 0; v < W_DIM; v++) {
            float o = th[v];
            if (o < mine || (o == mine && v < t)) r++;
        }
        rk[t] = r;          // sorted rank of hinge t (ties broken by index)
        ws[r] = mine;       // sorted hinge array
    }
    __syncthreads();

    if (t < H_DIM * NK) {
        int h = t / NK, k = t % NK;   // interval k: exactly k hinges < dist
        float A = 0.0f, B = b_out[h];
        for (int w = 0; w < W_DIM; w++) {
            float w1 = W_in[w], bv = b_in[w], ov = W_out[h * W_DIM + w];
            bool active = (w1 > 0.0f) ? (k > rk[w])
                        : (w1 < 0.0f) ? (k <= rk[w])
                        : (bv > 0.0f);
            if (active) { A += w1 * ov; B += bv * ov; }
        }
        ws[W_DIM + h * 2 * NK + 2 * k]     = A;
        ws[W_DIM + h * 2 * NK + 2 * k + 1] = B;
    }
}

// ---------------- main: wave-per-row, monotone-k PWL evaluation -------------
__global__ __launch_bounds__(256) void cope_fire_kernel(
    const float* __restrict__ attn,   // (H*S, S)
    const float* __restrict__ c_p,
    const float* __restrict__ Lm_p,
    const float* __restrict__ iL_p,
    const float* __restrict__ ws,
    float* __restrict__ out)
{
    const int t    = threadIdx.x;
    const int lane = t & 63;
    const int wave = t >> 6;
    const int row  = blockIdx.x * 4 + wave;       // one wave per row
    const int h    = blockIdx.x / (S_DIM / 4);    // block-uniform

    // sh[0] = -inf sentinel; sh[1..32] = sorted hinges (so k indexes directly)
    __shared__ float  sh[1 + W_DIM];
    __shared__ float2 sAB[NK];

    if (t == 0)     sh[0] = -__builtin_inff();
    if (t < W_DIM)  sh[1 + t] = ws[t];
    if (t < NK) {
        const float* p = ws + W_DIM + h * 2 * NK + 2 * t;
        sAB[t] = make_float2(p[0], p[1]);
    }

    // uniform scalars for the first 3 search levels (sh[i] == ws[i-1])
    const float u16 = ws[15];
    const float u8a = ws[7],  u8b = ws[23];
    const float u4a = ws[3],  u4b = ws[11], u4c = ws[19], u4d = ws[27];
    const float c   = c_p[0];
    const float thr = fabsf(Lm_p[0] * iL_p[0]);

    // load 12 contiguous elements per lane; sigmoid
    const float* rowp = attn + (size_t)row * S_DIM + lane * 12;
    float4 v0 = *(const float4*)(rowp);
    float4 v1 = *(const float4*)(rowp + 4);
    float4 v2 = *(const float4*)(rowp + 8);
    float g[12] = { v0.x, v0.y, v0.z, v0.w, v1.x, v1.y, v1.z, v1.w,
                    v2.x, v2.y, v2.z, v2.w };
#pragma unroll
    for (int i = 0; i < 12; i++)
        g[i] = __builtin_amdgcn_rcpf(1.0f + __expf(-g[i]));

    // lane total + inclusive wave scan of lane totals
    float T0 = 0.0f;
#pragma unroll
    for (int i = 0; i < 12; i++) T0 += g[i];
    float P = T0;
#pragma unroll
    for (int d = 1; d < 64; d <<= 1) {
        float y = __shfl_up(P, d, 64);
        if (lane >= d) P += y;
    }
    const float total = __shfl(P, 63, 64);
    const float base  = total - P + T0;   // suffix sum at lane's first element

    const float den     = __logf(fabsf(c * fminf(total, thr)) + 1.0f) + EPS_F;
    const float inv_den = __builtin_amdgcn_rcpf(den);

    // dist for all 12 elements (in-place over g; keep g[i] for the running sum)
    float e = 0.0f;
#pragma unroll
    for (int i = 0; i < 12; i++) {
        float pos = base - e;             // strictly decreasing over i
        e += g[i];
        g[i] = __logf(fabsf(c * pos) + 1.0f) * inv_den;
    }

    __syncthreads();   // tables staged

    // ---- initial search for element 0 (largest dist): k = #{hinges < d} ----
    float d0 = g[0];
    int k = 0;
    if (u16 < d0) k = 16;
    float l2 = (k != 0) ? u8b : u8a;          // sh[k+8]
    if (l2 < d0) k += 8;
    float l3ab = (k & 8) ? u4b : u4a;
    float l3cd = (k & 8) ? u4d : u4c;
    float l3   = (k & 16) ? l3cd : l3ab;      // sh[k+4]
    if (l3 < d0) k += 4;
    if (sh[k + 2] < d0) k += 2;
    if (sh[k + 1] < d0) k += 1;
    if (sh[k + 1] < d0) k += 1;               // 33rd outcome -> k in [0,32]

    float o[12];
    {
        float2 ab = sAB[k];
        o[0] = fmaf(d0, ab.x, ab.y);
    }
    // ---- monotone walk for elements 1..11 (k only ever decreases) ----------
#pragma unroll
    for (int i = 1; i < 12; i++) {
        float d = g[i];
        if (sh[k] >= d) k--;                  // common case: at most one hinge
        while (sh[k] >= d) k--;               // rare; sentinel sh[0]=-inf stops
        float2 ab = sAB[k];
        o[i] = fmaf(d, ab.x, ab.y);
    }

    float* op = out + (size_t)row * S_DIM + lane * 12;
    *(float4*)(op)     = make_float4(o[0], o[1], o[2],  o[3]);
    *(float4*)(op + 4) = make_float4(o[4], o[5], o[6],  o[7]);
    *(float4*)(op + 8) = make_float4(o[8], o[9], o[10], o[11]);
}

extern "C" void kernel_launch(void* const* d_in, const int* in_sizes, int n_in,
                              void* d_out, int out_size, void* d_ws, size_t ws_size,
                              hipStream_t stream) {
    const float* attn  = (const float*)d_in[0];
    const float* W_in  = (const float*)d_in[1];
    const float* b_in  = (const float*)d_in[2];
    const float* W_out = (const float*)d_in[3];
    const float* b_out = (const float*)d_in[4];
    const float* c_p   = (const float*)d_in[5];
    const float* Lm_p  = (const float*)d_in[6];
    const float* iL_p  = (const float*)d_in[7];
    float* out = (float*)d_out;
    float* ws  = (float*)d_ws;

    cope_setup_kernel<<<1, 512, 0, stream>>>(W_in, b_in, W_out, b_out, ws);

    const int rows = H_DIM * S_DIM;            // 9216 rows, one wave each
    cope_fire_kernel<<<rows / 4, 256, 0, stream>>>(
        attn, c_p, Lm_p, iL_p, ws, out);
}